// Round 1
// baseline (512.097 us; speedup 1.0000x reference)
//
#include <hip/hip_runtime.h>
#include <math.h>

// NM-LSTM step, B=256, IN=HS=512, NM=1, fp32.
// d_out layout: h_new (256*512) | c_new (256*512) | hebb_new (256*512*512)

__device__ __forceinline__ float sigm(float x) { return 1.0f / (1.0f + __expf(-x)); }
__device__ __forceinline__ float tanh_fast(float x) { return 1.0f - 2.0f / (1.0f + __expf(2.0f * x)); }
__device__ __forceinline__ float clip2(float v) { return fminf(fmaxf(v, -2.0f), 2.0f); }

// ---------------------------------------------------------------------------
// Kernel 1: raw gates = [x|h] @ [W;U] + bias -> ws (256 x 2048), fp32.
// UNCHANGED from previous round (measured ~25 us by arithmetic; not the
// bottleneck this round — kept identical for attribution).
// ---------------------------------------------------------------------------
__global__ __launch_bounds__(256, 4)
void gates_gemm(const float* __restrict__ x, const float* __restrict__ h,
                const float* __restrict__ W, const float* __restrict__ U,
                const float* __restrict__ bias, float* __restrict__ gates)
{
    __shared__ float As[64][64];   // [k][row]
    __shared__ float Bs[64][40];   // [k][col], padded pitch 40 (160B, 16B-aligned)

    const int t     = threadIdx.x;
    const int bcol0 = blockIdx.x * 32;
    const int brow0 = blockIdx.y * 64;
    const int row   = t & 63;
    const int cg    = t >> 6;      // 0..3, 8 cols each

    float acc[8] = {};

    for (int ks = 0; ks < 16; ++ks) {
        const float* srcA;
        const float* srcB;
        int ka;
        if (ks < 8) { srcA = x; srcB = W; ka = ks * 64; }
        else        { srcA = h; srcB = U; ka = ks * 64 - 512; }

        float4 av[4];
        #pragma unroll
        for (int m = 0; m < 4; ++m)
            av[m] = *(const float4*)&srcA[(size_t)(brow0 + row) * 512 + ka + cg * 16 + m * 4];
        const int kr0 = t >> 3;        // 0..31
        const int c4  = t & 7;         // 0..7
        float4 bv0 = *(const float4*)&srcB[(size_t)(ka + kr0)      * 2048 + bcol0 + c4 * 4];
        float4 bv1 = *(const float4*)&srcB[(size_t)(ka + kr0 + 32) * 2048 + bcol0 + c4 * 4];

        __syncthreads();
        #pragma unroll
        for (int m = 0; m < 4; ++m) {
            As[cg * 16 + m * 4 + 0][row] = av[m].x;
            As[cg * 16 + m * 4 + 1][row] = av[m].y;
            As[cg * 16 + m * 4 + 2][row] = av[m].z;
            As[cg * 16 + m * 4 + 3][row] = av[m].w;
        }
        *(float4*)&Bs[kr0][c4 * 4]      = bv0;
        *(float4*)&Bs[kr0 + 32][c4 * 4] = bv1;
        __syncthreads();

        #pragma unroll
        for (int k = 0; k < 64; ++k) {
            const float a = As[k][row];
            const float4 b0 = *(const float4*)&Bs[k][cg * 8];
            const float4 b1 = *(const float4*)&Bs[k][cg * 8 + 4];
            acc[0] += a * b0.x; acc[1] += a * b0.y; acc[2] += a * b0.z; acc[3] += a * b0.w;
            acc[4] += a * b1.x; acc[5] += a * b1.y; acc[6] += a * b1.z; acc[7] += a * b1.w;
        }
    }

    const int colb = bcol0 + cg * 8;
    float4 o0, o1;
    o0.x = acc[0] + bias[colb + 0]; o0.y = acc[1] + bias[colb + 1];
    o0.z = acc[2] + bias[colb + 2]; o0.w = acc[3] + bias[colb + 3];
    o1.x = acc[4] + bias[colb + 4]; o1.y = acc[5] + bias[colb + 5];
    o1.z = acc[6] + bias[colb + 6]; o1.w = acc[7] + bias[colb + 7];
    float* gp = &gates[(size_t)(brow0 + row) * 2048 + colb];
    *(float4*)gp       = o0;
    *(float4*)(gp + 4) = o1;
}

// ---------------------------------------------------------------------------
// Kernel 2: fused hebb reduce + update + LSTM epilogue.
// RESTRUCTURED: slab 512x32 (was 512x64), r[8] float4 = 32 VGPRs (was 64),
// __launch_bounds__(512,8) targets <=64 VGPR -> 4 blocks/CU (was 2).
// Theory: phase-serialized load->reduce->epilogue->store left HBM idle ~45%
// of the time at 2 blocks/CU; 4 staggered blocks keep the bus busy.
// Grid: 256 b * 16 j-tiles (32 cols). Block: 512 threads.
// thread t: tj4 = t&7 (float4 col), ti = t>>3 (rows ti*8..ti*8+7).
// Wave load/store contiguity: 8 lanes x 16B = 128B = one full cache line.
// ---------------------------------------------------------------------------
__global__ __launch_bounds__(512, 8)
void hebb_fused(const float* __restrict__ h_t, const float* __restrict__ c_t,
                const float* __restrict__ hebb, const float* __restrict__ alpha,
                const float* __restrict__ nm_w, const float* __restrict__ nm_b,
                const float* __restrict__ mt_w, const float* __restrict__ mt_b,
                const float* __restrict__ gates, float* __restrict__ out)
{
    const int b   = blockIdx.x >> 4;
    const int jt  = blockIdx.x & 15;
    const int t   = threadIdx.x;
    const int tj4 = t & 7;     // float4 column group within 32-col tile
    const int ti  = t >> 3;    // row group (8 rows each), 0..63

    __shared__ __align__(16) float hsh[512];
    __shared__ float redm[512];
    __shared__ __align__(16) float red[64][36];   // pitch 36: 144B rows, 16B-aligned, ~2-way banks (free)
    __shared__ __align__(16) float upd[32];
    __shared__ float msh;

    // --- h row + nm partial FIRST: hsh stage then waits only on these two
    //     loads (vmcnt(8)), not on the slab; ps loop later drains r[k] under
    //     graduated vmcnt while trailing slab loads are still in flight. ---
    const float hv0 = h_t[(size_t)b * 512 + t];
    const float nw  = nm_w[t];

    // --- hebb slab load: 8 dwordx4 per thread (64KB/block) ---
    const float4* hb    = (const float4*)(hebb + (size_t)b * 262144);
    const int     cbase = jt * 8 + tj4;          // float4 column index, row pitch 128
    float4 r[8];
    #pragma unroll
    for (int k = 0; k < 8; ++k)
        r[k] = hb[(size_t)(ti * 8 + k) * 128 + cbase];

    hsh[t]  = hv0;
    redm[t] = hv0 * nw;
    __syncthreads();

    // --- m_t reduction on wave 0 (overlaps other waves' ps work) ---
    if (t < 64) {
        float v = 0.f;
        #pragma unroll
        for (int q = 0; q < 8; ++q) v += redm[t + q * 64];
        #pragma unroll
        for (int off = 32; off > 0; off >>= 1) v += __shfl_down(v, off);
        if (t == 0) msh = tanh_fast(v + nm_b[0]);
    }

    // --- column partial sums over this thread's 8 rows ---
    float4 ps = {0.f, 0.f, 0.f, 0.f};
    #pragma unroll
    for (int k = 0; k < 8; ++k) {
        const float hv = hsh[ti * 8 + k];
        ps.x += hv * r[k].x;
        ps.y += hv * r[k].y;
        ps.z += hv * r[k].z;
        ps.w += hv * r[k].w;
    }
    *(float4*)&red[ti][tj4 * 4] = ps;
    __syncthreads();   // also makes msh visible

    // --- finalize on wave 0: lanes 0-31 / 32-63 each sum half the row
    //     groups for column c, combine via shfl_xor(32), epilogue on c<32 ---
    if (t < 64) {
        const int c  = t & 31;
        const int hf = t >> 5;
        float s = 0.f;
        #pragma unroll
        for (int q = 0; q < 32; ++q) s += red[hf * 32 + q][c];
        s += __shfl_xor(s, 32);
        if (hf == 0) {
            const int j = jt * 32 + c;
            const size_t gb = (size_t)b * 2048;
            const float g  = tanh_fast(gates[gb + 1024 + j] + alpha[j] * s);
            const float mm = msh * mt_w[j] + mt_b[j];
            upd[c] = mm * g;
            const float it_ = sigm(gates[gb + j]);
            const float ft  = sigm(gates[gb + 512 + j]);
            const float ot  = sigm(gates[gb + 1536 + j]);
            const float cn  = ft * c_t[(size_t)b * 512 + j] + it_ * g;
            out[(size_t)b * 512 + j]          = ot * tanh_fast(cn);   // h_new
            out[131072 + (size_t)b * 512 + j] = cn;                   // c_new
        }
    }
    __syncthreads();

    // --- hebb update + clip + store ---
    const float4 u = *(const float4*)&upd[tj4 * 4];
    float4* ho = (float4*)(out + 262144 + (size_t)b * 262144);
    #pragma unroll
    for (int k = 0; k < 8; ++k) {
        const float hv = hsh[ti * 8 + k];
        float4 w;
        w.x = clip2(r[k].x + u.x * hv);
        w.y = clip2(r[k].y + u.y * hv);
        w.z = clip2(r[k].z + u.z * hv);
        w.w = clip2(r[k].w + u.w * hv);
        ho[(size_t)(ti * 8 + k) * 128 + cbase] = w;
    }
}

extern "C" void kernel_launch(void* const* d_in, const int* in_sizes, int n_in,
                              void* d_out, int out_size, void* d_ws, size_t ws_size,
                              hipStream_t stream)
{
    const float* x_t   = (const float*)d_in[0];
    const float* h_t   = (const float*)d_in[1];
    const float* c_t   = (const float*)d_in[2];
    const float* hebb  = (const float*)d_in[3];
    const float* W     = (const float*)d_in[4];
    const float* U     = (const float*)d_in[5];
    const float* bias  = (const float*)d_in[6];
    const float* alpha = (const float*)d_in[7];
    const float* nm_w  = (const float*)d_in[8];
    const float* nm_b  = (const float*)d_in[9];
    const float* mt_w  = (const float*)d_in[10];
    const float* mt_b  = (const float*)d_in[11];
    float* out   = (float*)d_out;
    float* gates = (float*)d_ws;   // 256*2048 fp32 = 2 MB raw gates

    dim3 g1(64, 4);   // 2048/32 col-tiles x 256/64 row-tiles = 256 blocks
    gates_gemm<<<g1, 256, 0, stream>>>(x_t, h_t, W, U, bias, gates);
    hebb_fused<<<4096, 512, 0, stream>>>(h_t, c_t, hebb, alpha, nm_w, nm_b,
                                         mt_w, mt_b, gates, out);
}